// Round 9
// baseline (1165.863 us; speedup 1.0000x reference)
//
#include <hip/hip_runtime.h>

#define NN 50000
#define NE 800000
#define HH 128
#define SCAN_BLK 256
#define NBLK ((NN + SCAN_BLK - 1) / SCAN_BLK)   // 196
#define NGB ((NN + 63) / 64)                    // 782 node-groups of 64
#define PSZ ((size_t)NN * 16)                   // halves per 16-col panel

typedef _Float16 half8 __attribute__((ext_vector_type(8)));
typedef _Float16 half4 __attribute__((ext_vector_type(4)));
typedef float floatx16 __attribute__((ext_vector_type(16)));

static inline size_t align256(size_t x) { return (x + 255) & ~(size_t)255; }

// ---------------- degree histogram ----------------
__global__ void k_deg(const int* __restrict__ dst, int* __restrict__ deg) {
    int e = blockIdx.x * 256 + threadIdx.x;
    if (e < NE) atomicAdd(&deg[dst[e]], 1);
}

// ---------------- two-level scan ----------------
__global__ void k_bsum(const int* __restrict__ deg, int* __restrict__ part) {
    __shared__ int sd[SCAN_BLK];
    int t = threadIdx.x;
    int i = blockIdx.x * SCAN_BLK + t;
    sd[t] = (i < NN) ? deg[i] : 0;
    __syncthreads();
    for (int off = SCAN_BLK / 2; off > 0; off >>= 1) {
        if (t < off) sd[t] += sd[t + off];
        __syncthreads();
    }
    if (t == 0) part[blockIdx.x] = sd[0];
}

__global__ void k_scanpart(const int* __restrict__ part, int* __restrict__ partoff) {
    __shared__ int sd[SCAN_BLK];
    int t = threadIdx.x;
    int v = (t < NBLK) ? part[t] : 0;
    sd[t] = v;
    __syncthreads();
    for (int off = 1; off < SCAN_BLK; off <<= 1) {
        int add = (t >= off) ? sd[t - off] : 0;
        __syncthreads();
        sd[t] += add;
        __syncthreads();
    }
    if (t < NBLK) partoff[t] = sd[t] - v;
}

__global__ void k_apply(const int* __restrict__ deg, const int* __restrict__ partoff,
                        int* __restrict__ offsets, float* __restrict__ dinv) {
    __shared__ int sd[SCAN_BLK];
    int t = threadIdx.x;
    int i = blockIdx.x * SCAN_BLK + t;
    int v = (i < NN) ? deg[i] : 0;
    sd[t] = v;
    __syncthreads();
    for (int off = 1; off < SCAN_BLK; off <<= 1) {
        int add = (t >= off) ? sd[t - off] : 0;
        __syncthreads();
        sd[t] += add;
        __syncthreads();
    }
    if (i < NN) {
        offsets[i] = partoff[blockIdx.x] + sd[t] - v;
        dinv[i] = (v > 0) ? rsqrtf((float)v) : 0.0f;
    }
    if (i == 0) offsets[NN] = NE;
}

// ---------------- CSR fill (sorted by dst): 4-byte src-only records ----------------
__global__ void k_fill(const int* __restrict__ src, const int* __restrict__ dst,
                       const int* __restrict__ offsets, int* __restrict__ cursor,
                       int* __restrict__ csrc) {
    int e = blockIdx.x * 256 + threadIdx.x;
    if (e >= NE) return;
    int s = src[e], d = dst[e];
    int pos = atomicAdd(&cursor[d], 1);
    csrc[offsets[d] + pos] = s;
}

// ---------------- convert x to fp16 (row-major, feeds GEMM A) ----------------
__global__ void k_cvt_x(const float* __restrict__ x, _Float16* __restrict__ xh) {
    int i = blockIdx.x * 256 + threadIdx.x;
    if (i * 4 < NN * HH) {
        float4 v = *(const float4*)(x + (size_t)i * 4);
        half4 h;
        h.x = (_Float16)v.x; h.y = (_Float16)v.y;
        h.z = (_Float16)v.z; h.w = (_Float16)v.w;
        *(half4*)(xh + (size_t)i * 4) = h;
    }
}

// ---------------- convert + transpose weights to fp16 k-major ----------------
__global__ void k_cvt_w(const float* __restrict__ W1, const float* __restrict__ W2,
                        const float* __restrict__ tw,
                        _Float16* __restrict__ W1tP, _Float16* __restrict__ W1tQ,
                        _Float16* __restrict__ W2t, _Float16* __restrict__ TWt) {
    int i = blockIdx.x * 256 + threadIdx.x;
    if (i < 16384) {
        int c = i >> 7, k = i & 127;
        W1tP[c * 128 + k] = (_Float16)W1[k * 128 + c];
        W1tQ[c * 128 + k] = (_Float16)W1[(128 + k) * 128 + c];
    } else if (i < 32768) {
        int j = i - 16384;
        int c = j >> 7, k = j & 127;
        W2t[c * 128 + k] = (_Float16)W2[k * 128 + c];
    } else if (i < 32768 + 3 * 65536) {
        int j = i - 32768;
        int L = j >> 16;
        int c = (j >> 9) & 127;
        int k = j & 511;
        TWt[(size_t)L * 65536 + c * 512 + k] =
            (_Float16)tw[(size_t)L * 65536 + (size_t)(k >> 7) * 16384 + (size_t)(k & 127) * 128 + c];
    }
}

// ---------------- MFMA GEMM ----------------
// A_MODE: 0 = row-major stride lda; 1 = 16-col panels [p][NN][16], p = k>>4.
// OUT_MODE: 0 = row-major stride ldo; 1 = 16-col panels, p = col>>4.
template <int KDIM, int A_MODE, int HAS_BIAS, int HAS_DEG, int RELU, int OUT_MODE, typename OutT>
__global__ __launch_bounds__(256) void k_mm(
    const _Float16* __restrict__ A, int lda,
    const _Float16* __restrict__ Bt,
    const float* __restrict__ bias, const int* __restrict__ deg,
    OutT* __restrict__ Out, int ldo, int nrows) {
    __shared__ _Float16 As[128 * 64];
    __shared__ _Float16 Bs[128 * 64];
    const int t = threadIdx.x;
    const int l = t & 63;
    const int w = t >> 6;
    const int wm = w >> 1, wn = w & 1;
    const int row0 = blockIdx.x * 128;

    floatx16 acc[2][2] = {};

    const int srow = t >> 3;   // 0..31
    const int sslot = t & 7;   // 8-half slot within 64-k chunk

    for (int c = 0; c < KDIM / 64; ++c) {
        __syncthreads();
#pragma unroll
        for (int p4 = 0; p4 < 4; ++p4) {
            int r = srow + p4 * 32;
            int g = row0 + r;
            uint4 v = make_uint4(0, 0, 0, 0);
            if (g < nrows) {
                if (A_MODE == 0) {
                    v = *(const uint4*)(A + (size_t)g * lda + c * 64 + sslot * 8);
                } else {
                    int k = c * 64 + sslot * 8;
                    v = *(const uint4*)(A + ((size_t)(k >> 4) * NN + g) * 16 + (k & 15));
                }
            }
            *(uint4*)((char*)As + r * 128 + ((sslot * 16) ^ ((r & 7) << 4))) = v;
        }
#pragma unroll
        for (int p4 = 0; p4 < 4; ++p4) {
            int r = srow + p4 * 32;
            uint4 v = *(const uint4*)(Bt + (size_t)r * KDIM + c * 64 + sslot * 8);
            *(uint4*)((char*)Bs + r * 128 + ((sslot * 16) ^ ((r & 7) << 4))) = v;
        }
        __syncthreads();
#pragma unroll
        for (int ks = 0; ks < 4; ++ks) {
            const int koff = ks * 32 + (l >> 5) * 16;
            half8 a0, a1, b0, b1;
            { int r = wm * 64 + (l & 31);      a0 = *(const half8*)((const char*)As + r * 128 + (koff ^ ((r & 7) << 4))); }
            { int r = wm * 64 + 32 + (l & 31); a1 = *(const half8*)((const char*)As + r * 128 + (koff ^ ((r & 7) << 4))); }
            { int r = wn * 64 + (l & 31);      b0 = *(const half8*)((const char*)Bs + r * 128 + (koff ^ ((r & 7) << 4))); }
            { int r = wn * 64 + 32 + (l & 31); b1 = *(const half8*)((const char*)Bs + r * 128 + (koff ^ ((r & 7) << 4))); }
            acc[0][0] = __builtin_amdgcn_mfma_f32_32x32x16_f16(a0, b0, acc[0][0], 0, 0, 0);
            acc[0][1] = __builtin_amdgcn_mfma_f32_32x32x16_f16(a0, b1, acc[0][1], 0, 0, 0);
            acc[1][0] = __builtin_amdgcn_mfma_f32_32x32x16_f16(a1, b0, acc[1][0], 0, 0, 0);
            acc[1][1] = __builtin_amdgcn_mfma_f32_32x32x16_f16(a1, b1, acc[1][1], 0, 0, 0);
        }
    }

#pragma unroll
    for (int mf = 0; mf < 2; ++mf) {
#pragma unroll
        for (int nf = 0; nf < 2; ++nf) {
            const int col = wn * 64 + nf * 32 + (l & 31);
            const float bc = HAS_BIAS ? bias[col] : 0.0f;
#pragma unroll
            for (int r = 0; r < 16; ++r) {
                int row = wm * 64 + mf * 32 + 4 * (l >> 5) + (r & 3) + 8 * (r >> 2);
                int g = row0 + row;
                if (g < nrows) {
                    float v = acc[mf][nf][r];
                    if (HAS_BIAS) v += (HAS_DEG ? (float)deg[g] : 1.0f) * bc;
                    if (RELU) v = fmaxf(v, 0.0f);
                    if (OUT_MODE == 0) {
                        Out[(size_t)g * ldo + col] = (OutT)v;
                    } else {
                        Out[((size_t)(col >> 4) * NN + g) * 16 + (col & 15)] = (OutT)v;
                    }
                }
            }
        }
    }
}

// ---------------- MP edge pass, XCD-pinned 16-col chunks ----------------
// chunk = blockIdx & 7 (-> XCD), 64 nodes/block, 4 lanes x half4 per node.
// H_c[n] = sum_e lrelu(P_c[n] + Q_c[src]); in-place into P panel c.
__global__ __launch_bounds__(256) void k_edge_mp(_Float16* __restrict__ P,
                                                 const _Float16* __restrict__ Q,
                                                 const int* __restrict__ offsets,
                                                 const int* __restrict__ csrc) {
    const int t = threadIdx.x;
    const int c = blockIdx.x & 7;
    const int n = (blockIdx.x >> 3) * 64 + (t >> 2);
    if (n >= NN) return;
    const int off = (t & 3) * 4;
    _Float16* prow = P + ((size_t)c * NN + n) * 16 + off;
    const _Float16* Qb = Q + (size_t)c * NN * 16;
    half4 pv = *(const half4*)prow;
    const float p0 = (float)pv.x, p1 = (float)pv.y, p2 = (float)pv.z, p3 = (float)pv.w;
    const int beg = offsets[n], end = offsets[n + 1];
    float a0 = 0.f, a1 = 0.f, a2 = 0.f, a3 = 0.f;
    int i = beg;
#define LRELU4(vx, vy, vz, vw)                                        \
    a0 += ((vx) > 0.f) ? (vx) : 0.2f * (vx);                          \
    a1 += ((vy) > 0.f) ? (vy) : 0.2f * (vy);                          \
    a2 += ((vz) > 0.f) ? (vz) : 0.2f * (vz);                          \
    a3 += ((vw) > 0.f) ? (vw) : 0.2f * (vw);
    for (; i + 4 <= end; i += 4) {
        int s0 = __builtin_nontemporal_load(csrc + i + 0);
        int s1 = __builtin_nontemporal_load(csrc + i + 1);
        int s2 = __builtin_nontemporal_load(csrc + i + 2);
        int s3 = __builtin_nontemporal_load(csrc + i + 3);
        half4 q0 = *(const half4*)(Qb + (size_t)s0 * 16 + off);
        half4 q1 = *(const half4*)(Qb + (size_t)s1 * 16 + off);
        half4 q2 = *(const half4*)(Qb + (size_t)s2 * 16 + off);
        half4 q3 = *(const half4*)(Qb + (size_t)s3 * 16 + off);
        LRELU4(p0 + (float)q0.x, p1 + (float)q0.y, p2 + (float)q0.z, p3 + (float)q0.w)
        LRELU4(p0 + (float)q1.x, p1 + (float)q1.y, p2 + (float)q1.z, p3 + (float)q1.w)
        LRELU4(p0 + (float)q2.x, p1 + (float)q2.y, p2 + (float)q2.z, p3 + (float)q2.w)
        LRELU4(p0 + (float)q3.x, p1 + (float)q3.y, p2 + (float)q3.z, p3 + (float)q3.w)
    }
    for (; i < end; ++i) {
        int s = __builtin_nontemporal_load(csrc + i);
        half4 q = *(const half4*)(Qb + (size_t)s * 16 + off);
        LRELU4(p0 + (float)q.x, p1 + (float)q.y, p2 + (float)q.z, p3 + (float)q.w)
    }
#undef LRELU4
    half4 o;
    o.x = (_Float16)a0; o.y = (_Float16)a1; o.z = (_Float16)a2; o.w = (_Float16)a3;
    *(half4*)prow = o;
}

// ---------------- SpMM, XCD-pinned 16-col chunks ----------------
// Y_c[n] = dinv[n] * sum_e dinv[src] * X_c[src]
__global__ __launch_bounds__(256) void k_spmm(const _Float16* __restrict__ Xin,
                                              _Float16* __restrict__ Yout,
                                              const int* __restrict__ offsets,
                                              const int* __restrict__ csrc,
                                              const float* __restrict__ dinv) {
    const int t = threadIdx.x;
    const int c = blockIdx.x & 7;
    const int n = (blockIdx.x >> 3) * 64 + (t >> 2);
    if (n >= NN) return;
    const int off = (t & 3) * 4;
    const _Float16* Xb = Xin + (size_t)c * NN * 16;
    const int beg = offsets[n], end = offsets[n + 1];
    const float dn = dinv[n];
    float a0 = 0.f, a1 = 0.f, a2 = 0.f, a3 = 0.f;
    int i = beg;
    for (; i + 4 <= end; i += 4) {
        int s0 = __builtin_nontemporal_load(csrc + i + 0);
        int s1 = __builtin_nontemporal_load(csrc + i + 1);
        int s2 = __builtin_nontemporal_load(csrc + i + 2);
        int s3 = __builtin_nontemporal_load(csrc + i + 3);
        float n0 = dinv[s0], n1 = dinv[s1], n2 = dinv[s2], n3 = dinv[s3];
        half4 v0 = *(const half4*)(Xb + (size_t)s0 * 16 + off);
        half4 v1 = *(const half4*)(Xb + (size_t)s1 * 16 + off);
        half4 v2 = *(const half4*)(Xb + (size_t)s2 * 16 + off);
        half4 v3 = *(const half4*)(Xb + (size_t)s3 * 16 + off);
        a0 += n0 * (float)v0.x + n1 * (float)v1.x + n2 * (float)v2.x + n3 * (float)v3.x;
        a1 += n0 * (float)v0.y + n1 * (float)v1.y + n2 * (float)v2.y + n3 * (float)v3.y;
        a2 += n0 * (float)v0.z + n1 * (float)v1.z + n2 * (float)v2.z + n3 * (float)v3.z;
        a3 += n0 * (float)v0.w + n1 * (float)v1.w + n2 * (float)v2.w + n3 * (float)v3.w;
    }
    for (; i < end; ++i) {
        int s = __builtin_nontemporal_load(csrc + i);
        float nv = dinv[s];
        half4 v = *(const half4*)(Xb + (size_t)s * 16 + off);
        a0 += nv * (float)v.x; a1 += nv * (float)v.y;
        a2 += nv * (float)v.z; a3 += nv * (float)v.w;
    }
    half4 o;
    o.x = (_Float16)(dn * a0); o.y = (_Float16)(dn * a1);
    o.z = (_Float16)(dn * a2); o.w = (_Float16)(dn * a3);
    *(half4*)(Yout + ((size_t)c * NN + n) * 16 + off) = o;
}

extern "C" void kernel_launch(void* const* d_in, const int* in_sizes, int n_in,
                              void* d_out, int out_size, void* d_ws, size_t ws_size,
                              hipStream_t stream) {
    const float* x  = (const float*)d_in[0];
    const int*   ei = (const int*)d_in[1];
    const float* W1 = (const float*)d_in[2];
    const float* b1 = (const float*)d_in[3];
    const float* W2 = (const float*)d_in[4];
    const float* b2 = (const float*)d_in[5];
    const float* tw = (const float*)d_in[6];
    const float* tb = (const float*)d_in[7];
    float* out = (float*)d_out;

    const int* srcp = ei;
    const int* dstp = ei + NE;

    char* p = (char*)d_ws;
    auto alloc = [&](size_t bytes) { char* r = p; p += align256(bytes); return r; };
    int*       deg     = (int*)alloc((size_t)NN * 4);
    int*       cursor  = (int*)alloc((size_t)NN * 4);
    int*       offsets = (int*)alloc((size_t)(NN + 1) * 4);
    float*     dinv    = (float*)alloc((size_t)NN * 4);
    int*       part    = (int*)alloc((size_t)NBLK * 4);
    int*       partoff = (int*)alloc((size_t)NBLK * 4);
    int*       csrc    = (int*)alloc((size_t)NE * 4);
    _Float16*  xh      = (_Float16*)alloc((size_t)NN * HH * 2);
    _Float16*  Pp      = (_Float16*)alloc(8 * PSZ * 2);       // H/P: 8 panels
    _Float16*  Qp      = (_Float16*)alloc(8 * PSZ * 2);       // Q: 8 panels
    _Float16*  X4      = (_Float16*)alloc(32 * PSZ * 2);      // hops 0..3: 8 panels each
    _Float16*  W1tP    = (_Float16*)alloc(16384 * 2);
    _Float16*  W1tQ    = (_Float16*)alloc(16384 * 2);
    _Float16*  W2t     = (_Float16*)alloc(16384 * 2);
    _Float16*  TWt     = (_Float16*)alloc((size_t)3 * 65536 * 2);

    hipMemsetAsync(deg, 0, (size_t)NN * 4, stream);
    hipMemsetAsync(cursor, 0, (size_t)NN * 4, stream);

    k_deg<<<(NE + 255) / 256, 256, 0, stream>>>(dstp, deg);
    k_bsum<<<NBLK, SCAN_BLK, 0, stream>>>(deg, part);
    k_scanpart<<<1, SCAN_BLK, 0, stream>>>(part, partoff);
    k_apply<<<NBLK, SCAN_BLK, 0, stream>>>(deg, partoff, offsets, dinv);
    k_fill<<<(NE + 255) / 256, 256, 0, stream>>>(srcp, dstp, offsets, cursor, csrc);

    k_cvt_x<<<(NN * HH / 4 + 255) / 256, 256, 0, stream>>>(x, xh);
    k_cvt_w<<<(32768 + 3 * 65536 + 255) / 256, 256, 0, stream>>>(W1, W2, tw, W1tP, W1tQ, W2t, TWt);

    const int mmgrid = (NN + 127) / 128;
    const int ggrid = 8 * NGB;

    // MP layer: P panels = x@W1[:128]+b1 ; Q panels = x@W1[128:]
    k_mm<128, 0, 1, 0, 0, 1, _Float16><<<mmgrid, 256, 0, stream>>>(xh, HH, W1tP, b1, nullptr, Pp, 0, NN);
    k_mm<128, 0, 0, 0, 0, 1, _Float16><<<mmgrid, 256, 0, stream>>>(xh, HH, W1tQ, nullptr, nullptr, Qp, 0, NN);
    // H = sum_e lrelu(P+Q[s]) in-place into P panels
    k_edge_mp<<<ggrid, 256, 0, stream>>>(Pp, Qp, offsets, csrc);
    // x0 = H@W2 + deg*b2 -> X4 hop-0 panels
    k_mm<128, 1, 1, 1, 0, 1, _Float16><<<mmgrid, 256, 0, stream>>>(Pp, 0, W2t, b2, deg, X4, 0, NN);

    // 3 TAGConv layers: 3 XCD-pinned hops, then one wide K=512 GEMM
    for (int L = 0; L < 3; ++L) {
        const _Float16* Wt = TWt + (size_t)L * 65536;
        const float* bL = tb + (size_t)L * 128;
        k_spmm<<<ggrid, 256, 0, stream>>>(X4 + 0 * 8 * PSZ, X4 + 1 * 8 * PSZ, offsets, csrc, dinv);
        k_spmm<<<ggrid, 256, 0, stream>>>(X4 + 1 * 8 * PSZ, X4 + 2 * 8 * PSZ, offsets, csrc, dinv);
        k_spmm<<<ggrid, 256, 0, stream>>>(X4 + 2 * 8 * PSZ, X4 + 3 * 8 * PSZ, offsets, csrc, dinv);
        if (L < 2) {
            k_mm<512, 1, 1, 0, 1, 1, _Float16><<<mmgrid, 256, 0, stream>>>(X4, 0, Wt, bL, nullptr, X4, 0, NN);
        } else {
            k_mm<512, 1, 1, 0, 1, 0, float><<<mmgrid, 256, 0, stream>>>(X4, 0, Wt, bL, nullptr, out, HH, NN);
        }
    }
}

// Round 10
// 527.633 us; speedup vs baseline: 2.2096x; 2.2096x over previous
//
#include <hip/hip_runtime.h>

#define NN 50000
#define NE 800000
#define HH 128
#define SCAN_BLK 256
#define NBLK ((NN + SCAN_BLK - 1) / SCAN_BLK)   // 196
#define NB8 ((NN + 7) / 8)                      // 6250 (8 nodes/block)
#define NPT 6250                                // nodes per XCD team
#define TSB 128                                 // stripes per team
#define ECH ((NE + TSB - 1) / TSB)              // edges per stripe

typedef _Float16 half8 __attribute__((ext_vector_type(8)));
typedef _Float16 half4 __attribute__((ext_vector_type(4)));
typedef float floatx16 __attribute__((ext_vector_type(16)));

static inline size_t align256(size_t x) { return (x + 255) & ~(size_t)255; }

// ---------------- degree histogram, XCD-pinned teams ----------------
// team c = blockIdx&7 owns dst in [c*NPT,(c+1)*NPT); stripe = blockIdx>>3.
__global__ __launch_bounds__(256) void k_deg(const int* __restrict__ dst,
                                             int* __restrict__ deg) {
    const int c = blockIdx.x & 7;
    const int stripe = blockIdx.x >> 3;
    const int lo = c * NPT, hi = min(NN, lo + NPT);
    const int e0 = stripe * ECH;
    const int e1 = min(NE, e0 + ECH);
    for (int e = e0 + threadIdx.x; e < e1; e += 256) {
        int d = dst[e];
        if (d >= lo && d < hi) atomicAdd(&deg[d], 1);
    }
}

// ---------------- two-level scan ----------------
__global__ void k_bsum(const int* __restrict__ deg, int* __restrict__ part) {
    __shared__ int sd[SCAN_BLK];
    int t = threadIdx.x;
    int i = blockIdx.x * SCAN_BLK + t;
    sd[t] = (i < NN) ? deg[i] : 0;
    __syncthreads();
    for (int off = SCAN_BLK / 2; off > 0; off >>= 1) {
        if (t < off) sd[t] += sd[t + off];
        __syncthreads();
    }
    if (t == 0) part[blockIdx.x] = sd[0];
}

__global__ void k_scanpart(const int* __restrict__ part, int* __restrict__ partoff) {
    __shared__ int sd[SCAN_BLK];
    int t = threadIdx.x;
    int v = (t < NBLK) ? part[t] : 0;
    sd[t] = v;
    __syncthreads();
    for (int off = 1; off < SCAN_BLK; off <<= 1) {
        int add = (t >= off) ? sd[t - off] : 0;
        __syncthreads();
        sd[t] += add;
        __syncthreads();
    }
    if (t < NBLK) partoff[t] = sd[t] - v;
}

__global__ void k_apply(const int* __restrict__ deg, const int* __restrict__ partoff,
                        int* __restrict__ offsets, float* __restrict__ dinv) {
    __shared__ int sd[SCAN_BLK];
    int t = threadIdx.x;
    int i = blockIdx.x * SCAN_BLK + t;
    int v = (i < NN) ? deg[i] : 0;
    sd[t] = v;
    __syncthreads();
    for (int off = 1; off < SCAN_BLK; off <<= 1) {
        int add = (t >= off) ? sd[t - off] : 0;
        __syncthreads();
        sd[t] += add;
        __syncthreads();
    }
    if (i < NN) {
        offsets[i] = partoff[blockIdx.x] + sd[t] - v;
        dinv[i] = (v > 0) ? rsqrtf((float)v) : 0.0f;
    }
    if (i == 0) offsets[NN] = NE;
}

// ---------------- CSR fill, XCD-pinned teams: 4-byte src-only records ----------------
__global__ __launch_bounds__(256) void k_fill(const int* __restrict__ src,
                                              const int* __restrict__ dst,
                                              const int* __restrict__ offsets,
                                              int* __restrict__ cursor,
                                              int* __restrict__ csrc) {
    const int c = blockIdx.x & 7;
    const int stripe = blockIdx.x >> 3;
    const int lo = c * NPT, hi = min(NN, lo + NPT);
    const int e0 = stripe * ECH;
    const int e1 = min(NE, e0 + ECH);
    for (int e = e0 + threadIdx.x; e < e1; e += 256) {
        int d = dst[e];
        if (d >= lo && d < hi) {
            int pos = atomicAdd(&cursor[d], 1);
            csrc[offsets[d] + pos] = src[e];
        }
    }
}

// ---------------- convert x to fp16 ----------------
__global__ void k_cvt_x(const float* __restrict__ x, _Float16* __restrict__ xh) {
    int i = blockIdx.x * 256 + threadIdx.x;
    if (i * 4 < NN * HH) {
        float4 v = *(const float4*)(x + (size_t)i * 4);
        half4 h;
        h.x = (_Float16)v.x; h.y = (_Float16)v.y;
        h.z = (_Float16)v.z; h.w = (_Float16)v.w;
        *(half4*)(xh + (size_t)i * 4) = h;
    }
}

// ---------------- convert + transpose weights to fp16 k-major ----------------
__global__ void k_cvt_w(const float* __restrict__ W1, const float* __restrict__ W2,
                        const float* __restrict__ tw,
                        _Float16* __restrict__ W1tP, _Float16* __restrict__ W1tQ,
                        _Float16* __restrict__ W2t, _Float16* __restrict__ TWt) {
    int i = blockIdx.x * 256 + threadIdx.x;
    if (i < 16384) {
        int c = i >> 7, k = i & 127;
        W1tP[c * 128 + k] = (_Float16)W1[k * 128 + c];
        W1tQ[c * 128 + k] = (_Float16)W1[(128 + k) * 128 + c];
    } else if (i < 32768) {
        int j = i - 16384;
        int c = j >> 7, k = j & 127;
        W2t[c * 128 + k] = (_Float16)W2[k * 128 + c];
    } else if (i < 32768 + 3 * 65536) {
        int j = i - 32768;
        int L = j >> 16;
        int c = (j >> 9) & 127;
        int k = j & 511;
        TWt[(size_t)L * 65536 + c * 512 + k] =
            (_Float16)tw[(size_t)L * 65536 + (size_t)(k >> 7) * 16384 + (size_t)(k & 127) * 128 + c];
    }
}

// ---------------- MFMA GEMM (round-4/8 version, verified) ----------------
template <int KDIM, int HAS_BIAS, int HAS_DEG, int RELU, typename OutT>
__global__ __launch_bounds__(256) void k_mm(
    const _Float16* __restrict__ A, int lda,
    const _Float16* __restrict__ Bt,
    const float* __restrict__ bias, const int* __restrict__ deg,
    OutT* __restrict__ Out, int ldo, int nrows) {
    __shared__ _Float16 As[128 * 64];
    __shared__ _Float16 Bs[128 * 64];
    const int t = threadIdx.x;
    const int l = t & 63;
    const int w = t >> 6;
    const int wm = w >> 1, wn = w & 1;
    const int row0 = blockIdx.x * 128;

    floatx16 acc[2][2] = {};

    const int srow = t >> 3;
    const int sslot = t & 7;

    for (int c = 0; c < KDIM / 64; ++c) {
        __syncthreads();
#pragma unroll
        for (int p = 0; p < 4; ++p) {
            int r = srow + p * 32;
            int g = row0 + r;
            uint4 v = make_uint4(0, 0, 0, 0);
            if (g < nrows) v = *(const uint4*)(A + (size_t)g * lda + c * 64 + sslot * 8);
            *(uint4*)((char*)As + r * 128 + ((sslot * 16) ^ ((r & 7) << 4))) = v;
        }
#pragma unroll
        for (int p = 0; p < 4; ++p) {
            int r = srow + p * 32;
            uint4 v = *(const uint4*)(Bt + (size_t)r * KDIM + c * 64 + sslot * 8);
            *(uint4*)((char*)Bs + r * 128 + ((sslot * 16) ^ ((r & 7) << 4))) = v;
        }
        __syncthreads();
#pragma unroll
        for (int ks = 0; ks < 4; ++ks) {
            const int koff = ks * 32 + (l >> 5) * 16;
            half8 a0, a1, b0, b1;
            { int r = wm * 64 + (l & 31);      a0 = *(const half8*)((const char*)As + r * 128 + (koff ^ ((r & 7) << 4))); }
            { int r = wm * 64 + 32 + (l & 31); a1 = *(const half8*)((const char*)As + r * 128 + (koff ^ ((r & 7) << 4))); }
            { int r = wn * 64 + (l & 31);      b0 = *(const half8*)((const char*)Bs + r * 128 + (koff ^ ((r & 7) << 4))); }
            { int r = wn * 64 + 32 + (l & 31); b1 = *(const half8*)((const char*)Bs + r * 128 + (koff ^ ((r & 7) << 4))); }
            acc[0][0] = __builtin_amdgcn_mfma_f32_32x32x16_f16(a0, b0, acc[0][0], 0, 0, 0);
            acc[0][1] = __builtin_amdgcn_mfma_f32_32x32x16_f16(a0, b1, acc[0][1], 0, 0, 0);
            acc[1][0] = __builtin_amdgcn_mfma_f32_32x32x16_f16(a1, b0, acc[1][0], 0, 0, 0);
            acc[1][1] = __builtin_amdgcn_mfma_f32_32x32x16_f16(a1, b1, acc[1][1], 0, 0, 0);
        }
    }

#pragma unroll
    for (int mf = 0; mf < 2; ++mf) {
#pragma unroll
        for (int nf = 0; nf < 2; ++nf) {
            const int col = wn * 64 + nf * 32 + (l & 31);
            const float bc = HAS_BIAS ? bias[col] : 0.0f;
#pragma unroll
            for (int r = 0; r < 16; ++r) {
                int row = wm * 64 + mf * 32 + 4 * (l >> 5) + (r & 3) + 8 * (r >> 2);
                int g = row0 + row;
                if (g < nrows) {
                    float v = acc[mf][nf][r];
                    if (HAS_BIAS) v += (HAS_DEG ? (float)deg[g] : 1.0f) * bc;
                    if (RELU) v = fmaxf(v, 0.0f);
                    Out[(size_t)g * ldo + col] = (OutT)v;
                }
            }
        }
    }
}

// ---------------- MP edge pass over PQ[N,256] fp16, 8 nodes/block, 32 lanes x half4 ----------------
__global__ __launch_bounds__(256) void k_edge_mp(_Float16* __restrict__ PQ,
                                                 const int* __restrict__ offsets,
                                                 const int* __restrict__ csrc) {
    const int t = threadIdx.x;
    const int n = blockIdx.x * 8 + (t >> 5);
    if (n >= NN) return;
    const int lane = t & 31;
    const int beg = offsets[n], end = offsets[n + 1];
    half4 p4 = *(const half4*)(PQ + (size_t)n * 256 + lane * 4);
    const float p0 = (float)p4.x, p1 = (float)p4.y, p2 = (float)p4.z, p3 = (float)p4.w;
    float a0 = 0.f, a1 = 0.f, a2 = 0.f, a3 = 0.f;
    int i = beg;
#define LRELU4(vx, vy, vz, vw)                                        \
    a0 += ((vx) > 0.f) ? (vx) : 0.2f * (vx);                          \
    a1 += ((vy) > 0.f) ? (vy) : 0.2f * (vy);                          \
    a2 += ((vz) > 0.f) ? (vz) : 0.2f * (vz);                          \
    a3 += ((vw) > 0.f) ? (vw) : 0.2f * (vw);
    for (; i + 4 <= end; i += 4) {
        int s0 = csrc[i + 0], s1 = csrc[i + 1], s2 = csrc[i + 2], s3 = csrc[i + 3];
        half4 q0 = *(const half4*)(PQ + (size_t)s0 * 256 + 128 + lane * 4);
        half4 q1 = *(const half4*)(PQ + (size_t)s1 * 256 + 128 + lane * 4);
        half4 q2 = *(const half4*)(PQ + (size_t)s2 * 256 + 128 + lane * 4);
        half4 q3 = *(const half4*)(PQ + (size_t)s3 * 256 + 128 + lane * 4);
        LRELU4(p0 + (float)q0.x, p1 + (float)q0.y, p2 + (float)q0.z, p3 + (float)q0.w)
        LRELU4(p0 + (float)q1.x, p1 + (float)q1.y, p2 + (float)q1.z, p3 + (float)q1.w)
        LRELU4(p0 + (float)q2.x, p1 + (float)q2.y, p2 + (float)q2.z, p3 + (float)q2.w)
        LRELU4(p0 + (float)q3.x, p1 + (float)q3.y, p2 + (float)q3.z, p3 + (float)q3.w)
    }
    for (; i < end; ++i) {
        int s = csrc[i];
        half4 q = *(const half4*)(PQ + (size_t)s * 256 + 128 + lane * 4);
        LRELU4(p0 + (float)q.x, p1 + (float)q.y, p2 + (float)q.z, p3 + (float)q.w)
    }
#undef LRELU4
    half4 o;
    o.x = (_Float16)a0; o.y = (_Float16)a1; o.z = (_Float16)a2; o.w = (_Float16)a3;
    *(half4*)(PQ + (size_t)n * 256 + lane * 4) = o;
}

// ---------------- SpMM, 8 nodes/block (32 lanes x half4), X4 stride 512 ----------------
__global__ __launch_bounds__(256) void k_spmm(const _Float16* __restrict__ Xin,
                                              _Float16* __restrict__ Yout,
                                              const int* __restrict__ offsets,
                                              const int* __restrict__ csrc,
                                              const float* __restrict__ dinv) {
    const int t = threadIdx.x;
    const int n = blockIdx.x * 8 + (t >> 5);
    if (n >= NN) return;
    const int lane = t & 31;
    const int beg = offsets[n], end = offsets[n + 1];
    const float dn = dinv[n];
    float a0 = 0.f, a1 = 0.f, a2 = 0.f, a3 = 0.f;
    int i = beg;
    for (; i + 4 <= end; i += 4) {
        int s0 = csrc[i + 0], s1 = csrc[i + 1], s2 = csrc[i + 2], s3 = csrc[i + 3];
        float n0 = dinv[s0], n1 = dinv[s1], n2 = dinv[s2], n3 = dinv[s3];
        half4 v0 = *(const half4*)(Xin + (size_t)s0 * 512 + lane * 4);
        half4 v1 = *(const half4*)(Xin + (size_t)s1 * 512 + lane * 4);
        half4 v2 = *(const half4*)(Xin + (size_t)s2 * 512 + lane * 4);
        half4 v3 = *(const half4*)(Xin + (size_t)s3 * 512 + lane * 4);
        a0 += n0 * (float)v0.x + n1 * (float)v1.x + n2 * (float)v2.x + n3 * (float)v3.x;
        a1 += n0 * (float)v0.y + n1 * (float)v1.y + n2 * (float)v2.y + n3 * (float)v3.y;
        a2 += n0 * (float)v0.z + n1 * (float)v1.z + n2 * (float)v2.z + n3 * (float)v3.z;
        a3 += n0 * (float)v0.w + n1 * (float)v1.w + n2 * (float)v2.w + n3 * (float)v3.w;
    }
    for (; i < end; ++i) {
        int s = csrc[i];
        float nv = dinv[s];
        half4 v = *(const half4*)(Xin + (size_t)s * 512 + lane * 4);
        a0 += nv * (float)v.x; a1 += nv * (float)v.y;
        a2 += nv * (float)v.z; a3 += nv * (float)v.w;
    }
    half4 o;
    o.x = (_Float16)(dn * a0); o.y = (_Float16)(dn * a1);
    o.z = (_Float16)(dn * a2); o.w = (_Float16)(dn * a3);
    *(half4*)(Yout + (size_t)n * 512 + lane * 4) = o;
}

extern "C" void kernel_launch(void* const* d_in, const int* in_sizes, int n_in,
                              void* d_out, int out_size, void* d_ws, size_t ws_size,
                              hipStream_t stream) {
    const float* x  = (const float*)d_in[0];
    const int*   ei = (const int*)d_in[1];
    const float* W1 = (const float*)d_in[2];
    const float* b1 = (const float*)d_in[3];
    const float* W2 = (const float*)d_in[4];
    const float* b2 = (const float*)d_in[5];
    const float* tw = (const float*)d_in[6];
    const float* tb = (const float*)d_in[7];
    float* out = (float*)d_out;

    const int* srcp = ei;
    const int* dstp = ei + NE;

    char* p = (char*)d_ws;
    auto alloc = [&](size_t bytes) { char* r = p; p += align256(bytes); return r; };
    int*       deg     = (int*)alloc((size_t)NN * 4);
    int*       cursor  = (int*)alloc((size_t)NN * 4);
    int*       offsets = (int*)alloc((size_t)(NN + 1) * 4);
    float*     dinv    = (float*)alloc((size_t)NN * 4);
    int*       part    = (int*)alloc((size_t)NBLK * 4);
    int*       partoff = (int*)alloc((size_t)NBLK * 4);
    int*       csrc    = (int*)alloc((size_t)NE * 4);
    _Float16*  xh      = (_Float16*)alloc((size_t)NN * HH * 2);
    _Float16*  PQ      = (_Float16*)alloc((size_t)NN * 256 * 2);
    _Float16*  X4      = (_Float16*)alloc((size_t)NN * 512 * 2);
    _Float16*  W1tP    = (_Float16*)alloc(16384 * 2);
    _Float16*  W1tQ    = (_Float16*)alloc(16384 * 2);
    _Float16*  W2t     = (_Float16*)alloc(16384 * 2);
    _Float16*  TWt     = (_Float16*)alloc((size_t)3 * 65536 * 2);

    hipMemsetAsync(deg, 0, (size_t)NN * 4, stream);
    hipMemsetAsync(cursor, 0, (size_t)NN * 4, stream);

    k_deg<<<8 * TSB, 256, 0, stream>>>(dstp, deg);
    k_bsum<<<NBLK, SCAN_BLK, 0, stream>>>(deg, part);
    k_scanpart<<<1, SCAN_BLK, 0, stream>>>(part, partoff);
    k_apply<<<NBLK, SCAN_BLK, 0, stream>>>(deg, partoff, offsets, dinv);
    k_fill<<<8 * TSB, 256, 0, stream>>>(srcp, dstp, offsets, cursor, csrc);

    k_cvt_x<<<(NN * HH / 4 + 255) / 256, 256, 0, stream>>>(x, xh);
    k_cvt_w<<<(32768 + 3 * 65536 + 255) / 256, 256, 0, stream>>>(W1, W2, tw, W1tP, W1tQ, W2t, TWt);

    const int mmgrid = (NN + 127) / 128;

    // MP layer
    k_mm<128, 1, 0, 0, _Float16><<<mmgrid, 256, 0, stream>>>(xh, HH, W1tP, b1, nullptr, PQ, 256, NN);
    k_mm<128, 0, 0, 0, _Float16><<<mmgrid, 256, 0, stream>>>(xh, HH, W1tQ, nullptr, nullptr, PQ + 128, 256, NN);
    k_edge_mp<<<NB8, 256, 0, stream>>>(PQ, offsets, csrc);
    k_mm<128, 1, 1, 0, _Float16><<<mmgrid, 256, 0, stream>>>(PQ, 256, W2t, b2, deg, X4, 512, NN);

    // 3 TAGConv layers
    for (int L = 0; L < 3; ++L) {
        const _Float16* Wt = TWt + (size_t)L * 65536;
        const float* bL = tb + (size_t)L * 128;
        k_spmm<<<NB8, 256, 0, stream>>>(X4 + 0,   X4 + 128, offsets, csrc, dinv);
        k_spmm<<<NB8, 256, 0, stream>>>(X4 + 128, X4 + 256, offsets, csrc, dinv);
        k_spmm<<<NB8, 256, 0, stream>>>(X4 + 256, X4 + 384, offsets, csrc, dinv);
        if (L < 2) {
            k_mm<512, 1, 0, 1, _Float16><<<mmgrid, 256, 0, stream>>>(X4, 512, Wt, bL, nullptr, X4, 512, NN);
        } else {
            k_mm<512, 1, 0, 1, float><<<mmgrid, 256, 0, stream>>>(X4, 512, Wt, bL, nullptr, out, HH, NN);
        }
    }
}